// Round 9
// baseline (3235.109 us; speedup 1.0000x reference)
//
#include <hip/hip_runtime.h>

#define D_IN 8
#define D_MODEL 1024
#define DEPTH 12
#define D_INNER 2048
#define D_STATE 16
#define D_CONV 4
#define DT_RANK 64
#define BATCH 512

typedef unsigned short ushort_t;
typedef unsigned int uint_t;
typedef __attribute__((ext_vector_type(8))) short short8;
typedef __attribute__((ext_vector_type(16))) float f32x16;

__device__ __forceinline__ float sigmoidf_(float x) { return 1.f / (1.f + expf(-x)); }
__device__ __forceinline__ float siluf_(float x) { return x * sigmoidf_(x); }
__device__ __forceinline__ float softplusf_(float x) { return fmaxf(x, 0.f) + log1pf(expf(-fabsf(x))); }

__device__ __forceinline__ float waveRedSum(float v) {
#pragma unroll
  for (int off = 32; off; off >>= 1) v += __shfl_xor(v, off);
  return v;
}

// ---- bf16 3-way split helpers (RNE) ----
__device__ __forceinline__ ushort_t f2bf(float x) {
  uint_t u = __float_as_uint(x);
  u += 0x7fffu + ((u >> 16) & 1u);
  return (ushort_t)(u >> 16);
}
__device__ __forceinline__ float bf2f(ushort_t h) { return __uint_as_float((uint_t)h << 16); }
__device__ __forceinline__ void split3(float x, ushort_t& s0, ushort_t& s1, ushort_t& s2) {
  s0 = f2bf(x); float r = x - bf2f(s0);
  s1 = f2bf(r); r -= bf2f(s1);
  s2 = f2bf(r);
}
__device__ __forceinline__ uint4 pack8(const ushort_t* u) {
  uint4 v;
  v.x = (uint_t)u[0] | ((uint_t)u[1] << 16);
  v.y = (uint_t)u[2] | ((uint_t)u[3] << 16);
  v.z = (uint_t)u[4] | ((uint_t)u[5] << 16);
  v.w = (uint_t)u[6] | ((uint_t)u[7] << 16);
  return v;
}

// Fragment-ordered layouts (ushort units):
//  A-frag: [mb][kt][(q*2+mf)*3+s][lane64][8]   chunk stride 512, tile stride 12*512
//  B-frag: [nb][kt][q*3+s][lane64][8]          chunk stride 512, tile stride 6*512
//  lane = hi*32 + lo ; A: lo = row&31, mf=(row>>5)&1 ; B: lo = n&31
//  k of lane's 8 ushorts = kt*32 + q*16 + hi*8 + [0..8)

// ---- weight pre-split into B-frag layout ----
__global__ __launch_bounds__(256) void k_presplit(const float* __restrict__ W,
    ushort_t* __restrict__ Bt, int K, int items) {  // items = Ntot*K/8
  const int KT = K >> 5;
  const int kpr = K >> 3;
  for (int i = blockIdx.x * 256 + threadIdx.x; i < items; i += gridDim.x * 256) {
    const int n = i / kpr, k0 = (i - n * kpr) * 8;
    const float* g = W + (size_t)n * K + k0;
    float fv[8];
    *(float4*)&fv[0] = *(const float4*)(g + 0);
    *(float4*)&fv[4] = *(const float4*)(g + 4);
    ushort_t u0[8], u1[8], u2[8];
#pragma unroll
    for (int j = 0; j < 8; ++j) split3(fv[j], u0[j], u1[j], u2[j]);
    const int nb = n >> 5, lo = n & 31;
    const int kt = k0 >> 5, q = (k0 >> 4) & 1, hi = (k0 >> 3) & 1;
    const size_t base = ((size_t)(nb * KT + kt) * 6 + q * 3) * 512 + (hi * 32 + lo) * 8;
    *(uint4*)&Bt[base]        = pack8(u0);
    *(uint4*)&Bt[base + 512]  = pack8(u1);
    *(uint4*)&Bt[base + 1024] = pack8(u2);
  }
}

// h[b,m] -> A-frag h_t (KT=32)
__global__ __launch_bounds__(256) void k_input_proj(const float* __restrict__ xt,
    const float* __restrict__ Win, const float* __restrict__ bin,
    ushort_t* __restrict__ h_t) {
  int idx = blockIdx.x * 256 + threadIdx.x;
  int b = idx >> 10, m = idx & 1023;
  float acc = bin[m];
  const float* xr = xt + b * D_IN;
  const float* wr = Win + m * D_IN;
#pragma unroll
  for (int k = 0; k < D_IN; ++k) acc += xr[k] * wr[k];
  ushort_t s0, s1, s2; split3(acc, s0, s1, s2);
  const int mb = b >> 6, mf = (b >> 5) & 1, lo = b & 31;
  const int kt = m >> 5, q = (m >> 4) & 1, hi = (m >> 3) & 1;
  const size_t base = ((size_t)(mb * 32 + kt) * 12 + (q * 2 + mf) * 3) * 512
                      + (hi * 32 + lo) * 8 + (m & 7);
  h_t[base] = s0; h_t[base + 512] = s1; h_t[base + 1024] = s2;
}

// Barrier-free streaming GEMM: P_partial[kb] = A . B^T over k-slice.
// Block = 4 independent waves, each owning a 64m x 32n tile; fragments loaded
// straight from fragment-ordered global layouts (1KB coalesced per load), no LDS.
template <int MBLK, int NBB, int KSPLIT, int KT>
__global__ __launch_bounds__(256, 5) void k_gemmf(
    const ushort_t* __restrict__ At, const ushort_t* __restrict__ Bt,
    float* __restrict__ P, int N) {
  const int t = threadIdx.x, lane = t & 63, w = t >> 6;

  constexpr int GRID = MBLK * NBB * KSPLIT;
  constexpr int KPW = KT / KSPLIT;
  const int id = blockIdx.x;
  const int swz = (id & 7) * (GRID >> 3) + (id >> 3);
  const int kb = swz / (MBLK * NBB);
  const int r2 = swz % (MBLK * NBB);
  const int mb = r2 % MBLK, nbB = r2 / MBLK;
  const int nb = nbB * 4 + w;

  f32x16 acc[2];
#pragma unroll
  for (int r = 0; r < 16; ++r) { acc[0][r] = 0.f; acc[1][r] = 0.f; }

  const ushort_t* pA = At + ((size_t)(mb * KT + kb * KPW) * 12) * 512 + lane * 8;
  const ushort_t* pB = Bt + ((size_t)(nb * KT + kb * KPW) * 6) * 512 + lane * 8;

#pragma unroll 2
  for (int kt = 0; kt < KPW; ++kt) {
#pragma unroll
    for (int q = 0; q < 2; ++q) {
      short8 a0 = *(const short8*)(pA + (q * 6 + 0) * 512);
      short8 a1 = *(const short8*)(pA + (q * 6 + 1) * 512);
      short8 a2 = *(const short8*)(pA + (q * 6 + 2) * 512);
      short8 a3 = *(const short8*)(pA + (q * 6 + 3) * 512);
      short8 a4 = *(const short8*)(pA + (q * 6 + 4) * 512);
      short8 a5 = *(const short8*)(pA + (q * 6 + 5) * 512);
      short8 b0 = *(const short8*)(pB + (q * 3 + 0) * 512);
      short8 b1 = *(const short8*)(pB + (q * 3 + 1) * 512);
      short8 b2 = *(const short8*)(pB + (q * 3 + 2) * 512);
      acc[0] = __builtin_amdgcn_mfma_f32_32x32x16_bf16(a0, b0, acc[0], 0, 0, 0);
      acc[0] = __builtin_amdgcn_mfma_f32_32x32x16_bf16(a0, b1, acc[0], 0, 0, 0);
      acc[0] = __builtin_amdgcn_mfma_f32_32x32x16_bf16(a1, b0, acc[0], 0, 0, 0);
      acc[0] = __builtin_amdgcn_mfma_f32_32x32x16_bf16(a1, b1, acc[0], 0, 0, 0);
      acc[0] = __builtin_amdgcn_mfma_f32_32x32x16_bf16(a2, b0, acc[0], 0, 0, 0);
      acc[0] = __builtin_amdgcn_mfma_f32_32x32x16_bf16(a0, b2, acc[0], 0, 0, 0);
      acc[1] = __builtin_amdgcn_mfma_f32_32x32x16_bf16(a3, b0, acc[1], 0, 0, 0);
      acc[1] = __builtin_amdgcn_mfma_f32_32x32x16_bf16(a3, b1, acc[1], 0, 0, 0);
      acc[1] = __builtin_amdgcn_mfma_f32_32x32x16_bf16(a4, b0, acc[1], 0, 0, 0);
      acc[1] = __builtin_amdgcn_mfma_f32_32x32x16_bf16(a4, b1, acc[1], 0, 0, 0);
      acc[1] = __builtin_amdgcn_mfma_f32_32x32x16_bf16(a5, b0, acc[1], 0, 0, 0);
      acc[1] = __builtin_amdgcn_mfma_f32_32x32x16_bf16(a3, b2, acc[1], 0, 0, 0);
    }
    pA += 12 * 512;
    pB += 6 * 512;
  }

  float* Pk = P + (size_t)kb * 512 * N;
  const int n = nb * 32 + (lane & 31);
#pragma unroll
  for (int mf = 0; mf < 2; ++mf)
#pragma unroll
    for (int r = 0; r < 16; ++r) {
      const int m = mb * 64 + mf * 32 + (r & 3) + 8 * (r >> 2) + 4 * (lane >> 5);
      Pk[(size_t)m * N + n] = acc[mf][r];
    }
}

// Fused: (sum 8 Pin partials) conv1d+SiLU -> x_proj -> dt_proj+softplus -> SSM -> gate.
// 1 batch row per block, 512 blocks. Writes y into A-frag layout (KT=64).
__global__ __launch_bounds__(256) void k_fused(
    const float* __restrict__ Pin,   // [8][512][4096]
    const float* __restrict__ cst, const float* __restrict__ sst,
    const float* __restrict__ cw, const float* __restrict__ cb,
    const float* __restrict__ xpw, const float* __restrict__ dtw, const float* __restrict__ dtb,
    const float* __restrict__ alog, const float* __restrict__ dpar,
    ushort_t* __restrict__ y_t) {
  __shared__ float sxc[D_INNER];
  __shared__ float sxdb[96];
  const int t = threadIdx.x;
  const int b = blockIdx.x;
  const size_t S = 2097152;

  for (int d = t; d < D_INNER; d += 256) {
    float4 c = *(const float4*)&cst[((size_t)b * D_INNER + d) * 4];
    float4 w = *(const float4*)&cw[d * 4];
    const size_t xi = (size_t)b * 4096 + d;
    float xv = 0.f;
#pragma unroll
    for (int p = 0; p < 8; ++p) xv += Pin[xi + p * S];
    float a = c.y * w.x + c.z * w.y + c.w * w.z + xv * w.w + cb[d];
    sxc[d] = siluf_(a);
  }
  __syncthreads();

  const int wave = t >> 6, lane = t & 63;
  for (int r = wave * 24; r < wave * 24 + 24; ++r) {
    const float* wr = &xpw[(size_t)r * D_INNER];
    float p0 = 0.f, p1 = 0.f, p2 = 0.f, p3 = 0.f;
    for (int k = lane; k < D_INNER; k += 256) {
      p0 += wr[k] * sxc[k];
      p1 += wr[k + 64] * sxc[k + 64];
      p2 += wr[k + 128] * sxc[k + 128];
      p3 += wr[k + 192] * sxc[k + 192];
    }
    float a = waveRedSum((p0 + p1) + (p2 + p3));
    if (lane == 0) sxdb[r] = a;
  }
  __syncthreads();

  const int mb = b >> 6, mf = (b >> 5) & 1, lo = b & 31;
  for (int d = t; d < D_INNER; d += 256) {
    float An[D_STATE];
#pragma unroll
    for (int n = 0; n < D_STATE; ++n) An[n] = -expf(alog[(size_t)d * D_STATE + n]);
    float dtr = dtb[d];
#pragma unroll
    for (int j4 = 0; j4 < DT_RANK / 4; ++j4) {
      float4 wv = *(const float4*)&dtw[(size_t)d * DT_RANK + j4 * 4];
      dtr += sxdb[j4 * 4] * wv.x + sxdb[j4 * 4 + 1] * wv.y +
             sxdb[j4 * 4 + 2] * wv.z + sxdb[j4 * 4 + 3] * wv.w;
    }
    float dtv = softplusf_(dtr);
    float xcv = sxc[d];
    float dx = dtv * xcv;
    const float* srow = &sst[((size_t)b * D_INNER + d) * D_STATE];
    float acc = 0.f;
#pragma unroll
    for (int n = 0; n < D_STATE; ++n) {
      float Bn = sxdb[DT_RANK + n];
      float Cn = sxdb[DT_RANK + D_STATE + n];
      float sNew = srow[n] * expf(dtv * An[n]) + dx * Bn;
      acc += sNew * Cn;
    }
    float yv = acc + dpar[d] * xcv;
    const size_t zi = (size_t)b * 4096 + D_INNER + d;
    float zv = 0.f;
#pragma unroll
    for (int p = 0; p < 8; ++p) zv += Pin[zi + p * S];
    yv *= siluf_(zv);
    ushort_t s0, s1, s2; split3(yv, s0, s1, s2);
    const int kt = d >> 5, q = (d >> 4) & 1, hi = (d >> 3) & 1;
    const size_t base = ((size_t)(mb * 64 + kt) * 12 + (q * 2 + mf) * 3) * 512
                        + (hi * 32 + lo) * 8 + (d & 7);
    y_t[base] = s0; y_t[base + 512] = s1; y_t[base + 1024] = s2;
  }
}

// h = sum of 16 out_proj partials; emit h fp32 + A-frag h_t (KT=32)
__global__ __launch_bounds__(256) void k_reduce_out(const float* __restrict__ P,
    float* __restrict__ h, ushort_t* __restrict__ h_t) {
  const int i = blockIdx.x * 256 + threadIdx.x;  // 131072 float4
  float4 a = ((const float4*)P)[i];
#pragma unroll
  for (int p = 1; p < 16; ++p) {
    float4 b = ((const float4*)P)[(size_t)p * 131072 + i];
    a.x += b.x; a.y += b.y; a.z += b.z; a.w += b.w;
  }
  ((float4*)h)[i] = a;
  float fv[4] = {a.x, a.y, a.z, a.w};
  ushort_t u0[4], u1[4], u2[4];
#pragma unroll
  for (int j = 0; j < 4; ++j) split3(fv[j], u0[j], u1[j], u2[j]);
  const int flat = i * 4;
  const int b = flat >> 10, k = flat & 1023;
  const int mb = b >> 6, mf = (b >> 5) & 1, lo = b & 31;
  const int kt = k >> 5, q = (k >> 4) & 1, hi = (k >> 3) & 1;
  const size_t base = ((size_t)(mb * 32 + kt) * 12 + (q * 2 + mf) * 3) * 512
                      + (hi * 32 + lo) * 8 + (k & 7);
  *(uint2*)&h_t[base]        = make_uint2((uint_t)u0[0] | ((uint_t)u0[1] << 16), (uint_t)u0[2] | ((uint_t)u0[3] << 16));
  *(uint2*)&h_t[base + 512]  = make_uint2((uint_t)u1[0] | ((uint_t)u1[1] << 16), (uint_t)u1[2] | ((uint_t)u1[3] << 16));
  *(uint2*)&h_t[base + 1024] = make_uint2((uint_t)u2[0] | ((uint_t)u2[1] << 16), (uint_t)u2[2] | ((uint_t)u2[3] << 16));
}

__global__ __launch_bounds__(256) void k_layernorm(const float* __restrict__ h,
    const float* __restrict__ lnw, const float* __restrict__ lnb, float* __restrict__ out) {
  __shared__ float red[4];
  const int b = blockIdx.x, t = threadIdx.x;
  const float* row = h + (size_t)b * D_MODEL;
  float4 x = *(const float4*)&row[t * 4];
  float s = x.x + x.y + x.z + x.w;
  s = waveRedSum(s);
  const int wave = t >> 6, lane = t & 63;
  if (lane == 0) red[wave] = s;
  __syncthreads();
  float mu = (red[0] + red[1] + red[2] + red[3]) * (1.f / 1024.f);
  float d0 = x.x - mu, d1 = x.y - mu, d2 = x.z - mu, d3 = x.w - mu;
  float q = d0 * d0 + d1 * d1 + d2 * d2 + d3 * d3;
  q = waveRedSum(q);
  __syncthreads();
  if (lane == 0) red[wave] = q;
  __syncthreads();
  float var = (red[0] + red[1] + red[2] + red[3]) * (1.f / 1024.f);
  float inv = 1.f / sqrtf(var + 1e-5f);
  float4 wv = *(const float4*)&lnw[t * 4];
  float4 bv = *(const float4*)&lnb[t * 4];
  float4 o;
  o.x = d0 * inv * wv.x + bv.x;
  o.y = d1 * inv * wv.y + bv.y;
  o.z = d2 * inv * wv.z + bv.z;
  o.w = d3 * inv * wv.w + bv.w;
  *(float4*)&out[(size_t)b * D_MODEL + t * 4] = o;
}

extern "C" void kernel_launch(void* const* d_in, const int* in_sizes, int n_in,
                              void* d_out, int out_size, void* d_ws, size_t ws_size,
                              hipStream_t stream) {
  const float* x_t  = (const float*)d_in[0];
  const float* cst  = (const float*)d_in[1];
  const float* sst  = (const float*)d_in[2];
  const float* Win  = (const float*)d_in[3];
  const float* bin  = (const float*)d_in[4];
  const float* ipw  = (const float*)d_in[5];
  const float* cw   = (const float*)d_in[6];
  const float* cb   = (const float*)d_in[7];
  const float* xpw  = (const float*)d_in[8];
  const float* dtw  = (const float*)d_in[9];
  const float* dtb  = (const float*)d_in[10];
  const float* alog = (const float*)d_in[11];
  const float* dpar = (const float*)d_in[12];
  const float* opw  = (const float*)d_in[13];
  const float* lnw  = (const float*)d_in[14];
  const float* lnb  = (const float*)d_in[15];

  float* ws   = (float*)d_ws;
  float* h    = ws;                         // 524288 f32
  float* Pin  = h + 524288;                 // 8 x 2097152 f32
  float* Pout = Pin;                        // aliased: 16 x 524288 f32 (disjoint in time)
  ushort_t* u = (ushort_t*)(Pin + 16777216);
  ushort_t* h_t = u;                        // 8*32*12*512   = 1572864
  ushort_t* y_t = h_t + 1572864;            // 8*64*12*512   = 3145728
  ushort_t* iw_t = y_t + 3145728;           // 12 * 128*32*6*512 = 150994944
  ushort_t* ow_t = iw_t + 150994944;        // 12 * 32*64*6*512  = 75497472

  k_presplit<<<2048, 256, 0, stream>>>(ipw, iw_t, 1024, 12 * 524288);
  k_presplit<<<2048, 256, 0, stream>>>(opw, ow_t, 2048, 12 * 262144);
  k_input_proj<<<2048, 256, 0, stream>>>(x_t, Win, bin, h_t);

  for (int l = 0; l < DEPTH; ++l) {
    const ushort_t* iw = iw_t + (size_t)l * 12582912;
    const ushort_t* ow = ow_t + (size_t)l * 6291456;
    // in_proj: Pin[8][512][4096] = h . ipw^T  (8mb x 32nbB x KSPLIT8 = 2048 blocks)
    k_gemmf<8, 32, 8, 32><<<2048, 256, 0, stream>>>(h_t, iw, Pin, 4096);
    k_fused<<<512, 256, 0, stream>>>(
        Pin,
        cst + (size_t)l * BATCH * D_INNER * D_CONV,
        sst + (size_t)l * BATCH * D_INNER * D_STATE,
        cw + (size_t)l * D_INNER * D_CONV, cb + (size_t)l * D_INNER,
        xpw + (size_t)l * 96 * D_INNER,
        dtw + (size_t)l * D_INNER * DT_RANK, dtb + (size_t)l * D_INNER,
        alog + (size_t)l * D_INNER * D_STATE, dpar + (size_t)l * D_INNER,
        y_t);
    // out_proj: Pout[16][512][1024] = y . opw^T  (8mb x 8nbB x KSPLIT16 = 1024 blocks)
    k_gemmf<8, 8, 16, 64><<<1024, 256, 0, stream>>>(y_t, ow, Pout, 1024);
    k_reduce_out<<<512, 256, 0, stream>>>(Pout, h, h_t);
  }

  k_layernorm<<<512, 256, 0, stream>>>(h, lnw, lnb, (float*)d_out);
}